// Round 5
// baseline (36.269 us; speedup 1.0000x reference)
//
#include <hip/hip_runtime.h>

#define D 64
#define K 1024
#define NVEC 65536
#define MB 64             // vectors per block
#define NBLK (NVEC / MB)  // 1024
#define WAVES 4
#define KPW (K / WAVES)   // 256 codes per wave
#define TILES (KPW / 16)  // 16
#define NG (MB / 16)      // 4 vector groups per wave

typedef __attribute__((ext_vector_type(8))) short bf16x8;
typedef __attribute__((ext_vector_type(4))) float f32x4;

__device__ inline unsigned short f2bf(float f) {
    unsigned u = __builtin_bit_cast(unsigned, f);
    return (unsigned short)((u + 0x7FFFu + ((u >> 16) & 1u)) >> 16);  // RNE
}

// ---------------------------------------------------------------------------
// Prep: codebook f32 -> bf16, plus biased negated half-norms: hb = 1 - 0.5||e||^2
// (bias makes scores strictly positive so packed-uint argmax works; it cancels
// in the loss via unpack.)
// ---------------------------------------------------------------------------
__global__ __launch_bounds__(256) void vq_prep(const float* __restrict__ emb,
                                               unsigned short* __restrict__ ebf,
                                               float* __restrict__ hb) {
    const int k = blockIdx.x * 256 + threadIdx.x;   // 0..1023
    const float4* e4 = reinterpret_cast<const float4*>(emb + (size_t)k * D);
    ushort4* o4 = reinterpret_cast<ushort4*>(ebf + (size_t)k * D);
    float s = 0.f;
#pragma unroll
    for (int i = 0; i < D / 4; ++i) {
        float4 v = e4[i];
        s = fmaf(v.x, v.x, s); s = fmaf(v.y, v.y, s);
        s = fmaf(v.z, v.z, s); s = fmaf(v.w, v.w, s);
        ushort4 b; b.x = f2bf(v.x); b.y = f2bf(v.y); b.z = f2bf(v.z); b.w = f2bf(v.w);
        o4[i] = b;
    }
    hb[k] = 1.0f - 0.5f * s;
}

// ---------------------------------------------------------------------------
// Main: MFMA score GEMM + packed argmax + gather/write + loss partial.
// 256 thr (4 waves), 64 vectors/block; wave w owns codes [w*256, w*256+256).
// score_packed = (bits(z.e + 1 - 0.5||e||^2) & ~1023) | code_idx ; argmax = max_i32.
// ---------------------------------------------------------------------------
__global__ __launch_bounds__(256) void vq_mfma(const float* __restrict__ z,
                                               const float* __restrict__ emb,
                                               const unsigned short* __restrict__ ebf,
                                               const float* __restrict__ hb,
                                               float* __restrict__ out,
                                               float* __restrict__ pP) {
    __shared__ __align__(16) char zl[MB * 128];   // 8 KB bf16 z-tile [v][d], XOR-swizzled
    __shared__ int   wv[WAVES * MB];
    __shared__ int   fin[MB];
    __shared__ float red[256];

    const int tid = threadIdx.x;
    const int blk = blockIdx.x;
    const int b   = blk >> 4;              // batch (16 blocks per batch)
    const int hw0 = (blk & 15) * MB;       // first spatial pos
    const float* zb = z + (size_t)b * (D * 1024) + hw0;   // zb[d*1024 + v]

    // ---- stage z tile: f32 [d][v] -> LDS bf16 [v][d] swizzled; f32 sum(z^2)
    float zacc = 0.f;
    {
        const int v4 = tid & 15;           // 4-vector group
        const int d4 = tid >> 4;           // 4-dim group
        float4 r[4];
#pragma unroll
        for (int i = 0; i < 4; ++i)
            r[i] = *reinterpret_cast<const float4*>(zb + (size_t)(d4 * 4 + i) * 1024 + v4 * 4);
        const float* rf = reinterpret_cast<const float*>(r);
#pragma unroll
        for (int n = 0; n < 16; ++n) zacc = fmaf(rf[n], rf[n], zacc);
#pragma unroll
        for (int j = 0; j < 4; ++j) {
            const int v = v4 * 4 + j;
            ushort4 pk;
            pk.x = f2bf(rf[0 * 4 + j]); pk.y = f2bf(rf[1 * 4 + j]);
            pk.z = f2bf(rf[2 * 4 + j]); pk.w = f2bf(rf[3 * 4 + j]);
            const int byte = v * 128 + ((d4 * 8) ^ ((v & 7) << 4));
            *reinterpret_cast<ushort4*>(zl + byte) = pk;
        }
    }
    __syncthreads();

    const int wave = tid >> 6;
    const int lane = tid & 63;
    const int l16  = lane & 15;
    const int lg   = lane >> 4;    // 0..3

    // ---- B-frags: this block's 64 vectors in registers
    bf16x8 bfr[NG][2];
#pragma unroll
    for (int g = 0; g < NG; ++g)
#pragma unroll
        for (int h = 0; h < 2; ++h) {
            const int v = g * 16 + l16;
            const int byte = v * 128 + (((h * 64) + lg * 16) ^ ((v & 7) << 4));
            bfr[g][h] = *reinterpret_cast<const bf16x8*>(zl + byte);
        }

    // ---- k-loop: 16 codes per tile, packed argmax
    int best[NG];
#pragma unroll
    for (int g = 0; g < NG; ++g) best[g] = 0;
    const int cw = wave * KPW;
#pragma unroll 4
    for (int kt = 0; kt < TILES; ++kt) {
        const int cbase = cw + kt * 16;
        const bf16x8 a0 = *reinterpret_cast<const bf16x8*>(ebf + (size_t)(cbase + l16) * 64 + lg * 8);
        const bf16x8 a1 = *reinterpret_cast<const bf16x8*>(ebf + (size_t)(cbase + l16) * 64 + 32 + lg * 8);
        const f32x4 ci = *reinterpret_cast<const f32x4*>(hb + cbase + lg * 4);  // 1 - 0.5||e||^2
        const int idx0 = cbase + lg * 4;
#pragma unroll
        for (int g = 0; g < NG; ++g) {
            f32x4 c = ci;
            c = __builtin_amdgcn_mfma_f32_16x16x32_bf16(a0, bfr[g][0], c, 0, 0, 0);
            c = __builtin_amdgcn_mfma_f32_16x16x32_bf16(a1, bfr[g][1], c, 0, 0, 0);
#pragma unroll
            for (int r = 0; r < 4; ++r) {
                const int pk = (int)((__builtin_bit_cast(unsigned, c[r]) & 0xFFFFFC00u)
                                     | (unsigned)(idx0 + r));
                best[g] = best[g] > pk ? best[g] : pk;
            }
        }
    }

    // ---- cross-lane argmax (over lg); packed -> single max
#pragma unroll
    for (int g = 0; g < NG; ++g) {
        int tv = best[g];
        int o = __shfl_xor(tv, 16, 64); tv = tv > o ? tv : o;
        o = __shfl_xor(tv, 32, 64);     tv = tv > o ? tv : o;
        if (lane < 16) wv[wave * MB + g * 16 + l16] = tv;
    }
    __syncthreads();

    // ---- cross-wave combine; unpack score for the loss
    float tcon = 0.f;
    if (tid < MB) {
        int tv = wv[tid];
#pragma unroll
        for (int w = 1; w < WAVES; ++w) {
            const int o = wv[w * MB + tid];
            tv = tv > o ? tv : o;
        }
        fin[tid] = tv & 1023;
        tcon = __builtin_bit_cast(float, (unsigned)tv & 0xFFFFFC00u) - 1.0f;  // z.e - 0.5||e||^2
    }
    __syncthreads();

    // ---- output: gather exact f32 code rows, write out[b][d][hw]
    {
        const int v  = tid & 63;
        const int dh = tid >> 6;              // 0..3, 16 dims each
        const int idx = fin[v];
        const float4* eq4 = reinterpret_cast<const float4*>(emb + (size_t)idx * D + dh * 16);
        float* ob = out + (size_t)b * (D * 1024) + hw0 + v;
#pragma unroll
        for (int i = 0; i < 4; ++i) {
            const float4 q = eq4[i];
            const int d = dh * 16 + i * 4;
            ob[(size_t)(d + 0) * 1024] = q.x;
            ob[(size_t)(d + 1) * 1024] = q.y;
            ob[(size_t)(d + 2) * 1024] = q.z;
            ob[(size_t)(d + 3) * 1024] = q.w;
        }
    }

    // ---- single block reduction: partial = sum(z^2) - 2*sum(t)
    red[tid] = zacc - 2.f * tcon;
    __syncthreads();
#pragma unroll
    for (int s = 128; s > 0; s >>= 1) {
        if (tid < s) red[tid] += red[tid + s];
        __syncthreads();
    }
    if (tid == 0) pP[blk] = red[0];
}

// ---------------------------------------------------------------------------
// Loss: 1.25 * sum(partials) / (NVEC*D)
// ---------------------------------------------------------------------------
__global__ __launch_bounds__(256) void vq_loss(const float* __restrict__ pP,
                                               float* __restrict__ loss_out) {
    __shared__ float red[256];
    float s = 0.f;
    for (int i = threadIdx.x; i < NBLK; i += 256) s += pP[i];
    red[threadIdx.x] = s;
    __syncthreads();
#pragma unroll
    for (int st = 128; st > 0; st >>= 1) {
        if (threadIdx.x < st) red[threadIdx.x] += red[threadIdx.x + st];
        __syncthreads();
    }
    if (threadIdx.x == 0)
        loss_out[0] = 1.25f * red[0] * (1.0f / (float)((size_t)NVEC * D));
}

extern "C" void kernel_launch(void* const* d_in, const int* in_sizes, int n_in,
                              void* d_out, int out_size, void* d_ws, size_t ws_size,
                              hipStream_t stream) {
    const float* z   = (const float*)d_in[0];   // [64, 64, 32, 32]
    const float* emb = (const float*)d_in[1];   // [1024, 64]
    float* out = (float*)d_out;                 // 4194304 quantized + 1 loss

    char* ws = (char*)d_ws;
    unsigned short* ebf = (unsigned short*)ws;            // 128 KB bf16 codebook
    float* hb = (float*)(ws + 131072);                    // 4 KB biased neg half-norms
    float* pP = (float*)(ws + 135168);                    // 4 KB block partials

    vq_prep<<<K / 256, 256, 0, stream>>>(emb, ebf, hb);
    vq_mfma<<<NBLK, 256, 0, stream>>>(z, emb, ebf, hb, out, pP);
    vq_loss<<<1, 256, 0, stream>>>(pP, out + (size_t)NVEC * D);
}